// Round 17
// baseline (229.885 us; speedup 1.0000x reference)
//
#include <hip/hip_runtime.h>

#define GN 32
#define MT 2048
#define CD 512
#define NSLOT 16
#define NTOKENS 65536
#define SCALE -1.4285714285714286f

typedef float f32x4 __attribute__((ext_vector_type(4)));
typedef float f32x2 __attribute__((ext_vector_type(2)));
typedef int i32x4 __attribute__((ext_vector_type(4)));
typedef int i32x8 __attribute__((ext_vector_type(8)));

// ---- OCP e4m3fn encode/decode: hardware cvt when available, manual fallback ----
__device__ __forceinline__ float fp82f_sw(unsigned b) {
  unsigned s = (b & 0x80u) << 24;
  unsigned em = b & 0x7fu;
  float v;
  if (em >= 8)
    v = __uint_as_float((((em >> 3) + 120u) << 23) | ((em & 7u) << 20));
  else
    v = (float)em * 0x1p-9f;
  return __uint_as_float(__float_as_uint(v) | s);
}

#if __has_builtin(__builtin_amdgcn_cvt_pk_f32_fp8)
template <bool HI>
__device__ __forceinline__ f32x2 fp8dec2(unsigned word) {
  return __builtin_amdgcn_cvt_pk_f32_fp8((int)word, HI);
}
#else
template <bool HI>
__device__ __forceinline__ f32x2 fp8dec2(unsigned word) {
  unsigned w = HI ? (word >> 16) : word;
  f32x2 r;
  r.x = fp82f_sw(w & 0xffu);
  r.y = fp82f_sw((w >> 8) & 0xffu);
  return r;
}
#endif

__device__ __forceinline__ unsigned char f2fp8_sw(float f) {
  unsigned s = (__float_as_uint(f) >> 24) & 0x80u;
  float a = fabsf(f);
  unsigned char r;
  if (a >= 0x1p-6f) {
    int e = (int)(__float_as_uint(a) >> 23) - 127;
    int qi = (int)rintf(__builtin_ldexpf(a, 3 - e));
    if (qi == 16) { qi = 8; ++e; }
    r = (unsigned char)(((e + 7) << 3) | (qi - 8));
  } else {
    r = (unsigned char)(int)rintf(a * 512.0f);
  }
  return (unsigned char)(r | s);
}

#if __has_builtin(__builtin_amdgcn_cvt_pk_fp8_f32)
__device__ __forceinline__ unsigned pk4fp8(float a, float b, float c, float d) {
  int w = __builtin_amdgcn_cvt_pk_fp8_f32(a, b, 0, false);
  w = __builtin_amdgcn_cvt_pk_fp8_f32(c, d, w, true);
  return (unsigned)w;
}
#else
__device__ __forceinline__ unsigned pk4fp8(float a, float b, float c, float d) {
  return (unsigned)f2fp8_sw(a) | ((unsigned)f2fp8_sw(b) << 8) |
         ((unsigned)f2fp8_sw(c) << 16) | ((unsigned)f2fp8_sw(d) << 24);
}
#endif

__device__ __forceinline__ void gload16(const void* g, const void* l) {
  __builtin_amdgcn_global_load_lds((const __attribute__((address_space(1))) unsigned*)g,
                                   (__attribute__((address_space(3))) unsigned*)(
                                       (unsigned long)l),
                                   16, 0, 0);
}

// K1: L2-normalize rows of [NTOKENS,512] fp32 -> fp8 e4m3 for BOTH inputs.
// 16 lanes per row, 4 rows per wave per iteration: 8 independent float4 loads
// per lane (8 KB/wave in flight, 4x prior) all feeding one reduction -> loads
// cannot be sunk; no LDS, no barriers. 4-step shfl reduce within 16-lane group.
#define NORMB 2048
__global__ __launch_bounds__(256) void k_norm2(const float* __restrict__ a,
                                               const float* __restrict__ b,
                                               unsigned char* __restrict__ oa,
                                               unsigned char* __restrict__ ob) {
  const int lane = threadIdx.x & 63;
  const int wv = blockIdx.x * 4 + (threadIdx.x >> 6);  // 0..8191
  const int c = lane & 15;  // column-lane within row
  const int r = lane >> 4;  // row within quad
#pragma unroll
  for (int it = 0; it < 4; ++it) {
    long row = (long)wv * 16 + it * 4 + r;  // 0..131071, exact cover
    const float* in = (row < NTOKENS) ? a : b;
    unsigned char* out = (row < NTOKENS) ? oa : ob;
    long rr = row & (NTOKENS - 1);
    const float4* src = reinterpret_cast<const float4*>(in + rr * CD);
    float4 v0 = src[c];
    float4 v1 = src[c + 16];
    float4 v2 = src[c + 32];
    float4 v3 = src[c + 48];
    float4 v4 = src[c + 64];
    float4 v5 = src[c + 80];
    float4 v6 = src[c + 96];
    float4 v7 = src[c + 112];
    float ss = v0.x * v0.x + v0.y * v0.y + v0.z * v0.z + v0.w * v0.w +
               v1.x * v1.x + v1.y * v1.y + v1.z * v1.z + v1.w * v1.w +
               v2.x * v2.x + v2.y * v2.y + v2.z * v2.z + v2.w * v2.w +
               v3.x * v3.x + v3.y * v3.y + v3.z * v3.z + v3.w * v3.w +
               v4.x * v4.x + v4.y * v4.y + v4.z * v4.z + v4.w * v4.w +
               v5.x * v5.x + v5.y * v5.y + v5.z * v5.z + v5.w * v5.w +
               v6.x * v6.x + v6.y * v6.y + v6.z * v6.z + v6.w * v6.w +
               v7.x * v7.x + v7.y * v7.y + v7.z * v7.z + v7.w * v7.w;
    ss += __shfl_xor(ss, 1);
    ss += __shfl_xor(ss, 2);
    ss += __shfl_xor(ss, 4);
    ss += __shfl_xor(ss, 8);
    float rn = 1.0f / fmaxf(sqrtf(ss), 1e-12f);
    unsigned* orow = (unsigned*)(out + rr * CD);
    orow[c] = pk4fp8(v0.x * rn, v0.y * rn, v0.z * rn, v0.w * rn);
    orow[c + 16] = pk4fp8(v1.x * rn, v1.y * rn, v1.z * rn, v1.w * rn);
    orow[c + 32] = pk4fp8(v2.x * rn, v2.y * rn, v2.z * rn, v2.w * rn);
    orow[c + 48] = pk4fp8(v3.x * rn, v3.y * rn, v3.z * rn, v3.w * rn);
    orow[c + 64] = pk4fp8(v4.x * rn, v4.y * rn, v4.z * rn, v4.w * rn);
    orow[c + 80] = pk4fp8(v5.x * rn, v5.y * rn, v5.z * rn, v5.w * rn);
    orow[c + 96] = pk4fp8(v6.x * rn, v6.y * rn, v6.z * rn, v6.w * rn);
    orow[c + 112] = pk4fp8(v7.x * rn, v7.y * rn, v7.z * rn, v7.w * rn);
  }
}

// K2: argmax over slot dim + per-(group,slot) histogram
__global__ __launch_bounds__(256) void k_grp(const float* __restrict__ masks,
                                             int* __restrict__ grp, int* __restrict__ cnt) {
  int t = blockIdx.x * 256 + threadIdx.x;
  int bt = t >> 10, n = t & 1023;
  const float* p = masks + (size_t)bt * NSLOT * 1024 + n;
  float bv = p[0];
  int bs = 0;
#pragma unroll
  for (int s = 1; s < NSLOT; ++s) {
    float v = p[(size_t)s * 1024];
    if (v > bv) { bv = v; bs = s; }
  }
  grp[t] = bs;
  atomicAdd(&cnt[(t >> 11) * NSLOT + bs], 1);
}

// K3a: partial fcsum via LDS-indexed accumulation (proven R8 version, hw decode).
#define FCH 64
#define NCH (MT / FCH)  // 32
__global__ __launch_bounds__(256, 4) void k_fcsum_part(const unsigned char* __restrict__ fc8,
                                                       const int* __restrict__ grp,
                                                       float* __restrict__ part) {
  __shared__ float accs[NSLOT * CD];
  __shared__ int gsh[FCH];
  int g = blockIdx.x >> 5;
  int ch = blockIdx.x & 31;
  int t = threadIdx.x;
  if (t < FCH) gsh[t] = grp[g * MT + ch * FCH + t];
#pragma unroll
  for (int i = 0; i < NSLOT * CD / 256; ++i) accs[i * 256 + t] = 0.f;
  __syncthreads();
  const unsigned char* base = fc8 + ((size_t)g * MT + ch * FCH) * CD + 2 * t;
#pragma unroll 4
  for (int n = 0; n < FCH; ++n) {
    unsigned u = *(const unsigned short*)(base + (size_t)n * CD);
    int gs = gsh[n];
    f32x2 v = fp8dec2<false>(u);
    float* p = &accs[gs * CD + 2 * t];
    p[0] += v.x;
    p[1] += v.y;
  }
  __syncthreads();
  float* dst = part + (size_t)(g * NCH + ch) * (NSLOT * CD);
#pragma unroll
  for (int i = 0; i < NSLOT * CD / 256; ++i) dst[i * 256 + t] = accs[i * 256 + t];
}

// K3b: reduce partials over the 32 chunks
__global__ __launch_bounds__(256) void k_fcsum_red(const float* __restrict__ part,
                                                   float* __restrict__ fcsum) {
  int idx = blockIdx.x * 256 + threadIdx.x;  // < GN*NSLOT*CD = 262144
  int g = idx >> 13;
  int sc = idx & 8191;
  float s = 0.f;
#pragma unroll
  for (int ch = 0; ch < NCH; ++ch)
    s += part[(size_t)(g * NCH + ch) * (NSLOT * CD) + sc];
  fcsum[idx] = s;
}

// K4: MX-fp8 256x256-tile pair kernel — exact R9 structure (99 us proven).
// Depth-2 schedules twice-failed on register budget (R6 hoist-spill, R15
// barrier-in-unroll spill) — schedule frozen at depth-1.
#define BM 256
#define BN 256
#define BKB 128
#define NTILE 32  // 8 col-tiles x 4 k-tiles

__global__ __launch_bounds__(512, 2) void k_pair(const unsigned char* __restrict__ ft8,
                                                 const unsigned char* __restrict__ fc8,
                                                 float* __restrict__ sexp_out) {
  extern __shared__ char smem[];  // A0[32K] A1[32K] B0[32K] B1[32K]

  const int b = blockIdx.x;
  const int xcd = b & 7;
  const int slot = b >> 3;
  const int g = (slot >> 3) * 8 + xcd;
  const int rt = slot & 7;
  const int r0 = rt * BM;

  const int tid = threadIdx.x;
  const int lane = tid & 63;
  const int wid = tid >> 6;
  const int wr = wid >> 2;   // 0..1
  const int wc = wid & 3;    // 0..3
  const int frow = lane & 15;
  const int l4 = lane >> 4;  // 0..3 -> k-block l4*32 bytes
  const int f7 = frow & 7;

  const unsigned char* Abase = ft8 + (size_t)g * MT * CD;
  const unsigned char* Bbase = fc8 + (size_t)g * MT * CD;

  const int lrow = lane >> 3;                  // 0..7
  const int koff = ((lane & 7) ^ lrow) << 4;   // pre-swizzled source chunk (bytes)

  const int c0off = ((2 * l4) ^ f7) << 4;
  const int c1off = ((2 * l4 + 1) ^ f7) << 4;
  const int baseA = (wr * 128 + frow) * 128;
  const int baseB = (wc * 64 + frow) * 128;

  f32x4 acc[8][4];
#pragma unroll
  for (int m = 0; m < 8; ++m)
#pragma unroll
    for (int n = 0; n < 4; ++n) acc[m][n] = (f32x4){0.f, 0.f, 0.f, 0.f};
  float sexp_loc[8][4];
#pragma unroll
  for (int m = 0; m < 8; ++m)
#pragma unroll
    for (int r = 0; r < 4; ++r) sexp_loc[m][r] = 0.f;

#define STAGE(TT, PB)                                                         \
  {                                                                           \
    const int kk_ = ((TT) & 3) * BKB;                                         \
    const int n0_ = ((TT) >> 2) * BN;                                         \
    char* dA_ = smem + (size_t)(PB)*32768;                                    \
    char* dB_ = smem + 65536 + (size_t)(PB)*32768;                            \
    _Pragma("unroll") for (int j_ = 0; j_ < 4; ++j_) {                        \
      const int rb_ = wid * 32 + j_ * 8;                                      \
      gload16(Abase + (size_t)(r0 + rb_ + lrow) * CD + kk_ + koff,            \
              dA_ + (size_t)rb_ * BKB);                                       \
      gload16(Bbase + (size_t)(n0_ + rb_ + lrow) * CD + kk_ + koff,           \
              dB_ + (size_t)rb_ * BKB);                                       \
    }                                                                         \
  }

  STAGE(0, 0)
  __syncthreads();

  int pb = 0;
  for (int t = 0; t < NTILE; ++t) {
    if (t + 1 < NTILE) STAGE(t + 1, pb ^ 1)

    const char* cA = smem + (size_t)pb * 32768;
    const char* cB = smem + 65536 + (size_t)pb * 32768;
    __builtin_amdgcn_s_setprio(1);
    i32x8 bfv[4];
#pragma unroll
    for (int n = 0; n < 4; ++n) {
      i32x4 lo = *(const i32x4*)(cB + baseB + n * 2048 + c0off);
      i32x4 hi = *(const i32x4*)(cB + baseB + n * 2048 + c1off);
      bfv[n] = __builtin_shufflevector(lo, hi, 0, 1, 2, 3, 4, 5, 6, 7);
    }
#pragma unroll
    for (int m = 0; m < 8; ++m) {
      i32x4 lo = *(const i32x4*)(cA + baseA + m * 2048 + c0off);
      i32x4 hi = *(const i32x4*)(cA + baseA + m * 2048 + c1off);
      i32x8 af = __builtin_shufflevector(lo, hi, 0, 1, 2, 3, 4, 5, 6, 7);
#pragma unroll
      for (int n = 0; n < 4; ++n)
        acc[m][n] = __builtin_amdgcn_mfma_scale_f32_16x16x128_f8f6f4(
            af, bfv[n], acc[m][n], 0, 0, 0, 0x7f7f7f7f, 0, 0x7f7f7f7f);
    }
    __builtin_amdgcn_s_setprio(0);

    if ((t & 3) == 3) {
#pragma unroll
      for (int m = 0; m < 8; ++m)
#pragma unroll
        for (int r = 0; r < 4; ++r) {
          float e = 0.f;
#pragma unroll
          for (int n = 0; n < 4; ++n) e += exp2f(acc[m][n][r] * 14.4269504089f);
          sexp_loc[m][r] += e;
        }
#pragma unroll
      for (int m = 0; m < 8; ++m)
#pragma unroll
        for (int n = 0; n < 4; ++n) acc[m][n] = (f32x4){0.f, 0.f, 0.f, 0.f};
    }

    __syncthreads();
    pb ^= 1;
  }
#undef STAGE

#pragma unroll
  for (int m = 0; m < 8; ++m)
#pragma unroll
    for (int r = 0; r < 4; ++r) {
      float v = sexp_loc[m][r];
      v += __shfl_xor(v, 1);
      v += __shfl_xor(v, 2);
      v += __shfl_xor(v, 4);
      v += __shfl_xor(v, 8);
      sexp_loc[m][r] = v;
    }
  __syncthreads();
  float* scr = (float*)smem;  // [8 waves][128 rows]
  if (frow == 0) {
#pragma unroll
    for (int m = 0; m < 8; ++m)
#pragma unroll
      for (int r = 0; r < 4; ++r) scr[wid * 128 + m * 16 + l4 * 4 + r] = sexp_loc[m][r];
  }
  __syncthreads();
  if (tid < 256) {
    int wrr = tid >> 7, rl = tid & 127;
    float s = scr[(wrr * 4 + 0) * 128 + rl] + scr[(wrr * 4 + 1) * 128 + rl] +
              scr[(wrr * 4 + 2) * 128 + rl] + scr[(wrr * 4 + 3) * 128 + rl];
    sexp_out[(size_t)g * MT + r0 + tid] = s;
  }
}

// K5: per-token loss fused with final mean (fp8 inputs, hw decode)
__global__ __launch_bounds__(256) void k_loss(const unsigned char* __restrict__ ft8,
                                              const unsigned char* __restrict__ fc8,
                                              const float* __restrict__ fcsum,
                                              const int* __restrict__ grp,
                                              const int* __restrict__ cnt,
                                              const float* __restrict__ sexp,
                                              float* __restrict__ out) {
  __shared__ float sh[4];
  int wid = threadIdx.x >> 6, lane = threadIdx.x & 63;
  float wsum = 0.f;
  for (int t = blockIdx.x * 4 + wid; t < NTOKENS; t += 4096) {
    int g = t >> 11;
    uint2 u1 = reinterpret_cast<const uint2*>(ft8 + (size_t)t * CD)[lane];
    uint2 u2 = reinterpret_cast<const uint2*>(fc8 + (size_t)t * CD)[lane];
    int gs = grp[t];
    const float4* srv = (const float4*)(fcsum + ((size_t)g * NSLOT + gs) * CD);
    float4 s0 = srv[2 * lane];
    float4 s1 = srv[2 * lane + 1];
    f32x2 a01 = fp8dec2<false>(u1.x), a23 = fp8dec2<true>(u1.x);
    f32x2 a45 = fp8dec2<false>(u1.y), a67 = fp8dec2<true>(u1.y);
    f32x2 c01 = fp8dec2<false>(u2.x), c23 = fp8dec2<true>(u2.x);
    f32x2 c45 = fp8dec2<false>(u2.y), c67 = fp8dec2<true>(u2.y);
    float d1 = a01.x * c01.x + a01.y * c01.y + a23.x * c23.x + a23.y * c23.y +
               a45.x * c45.x + a45.y * c45.y + a67.x * c67.x + a67.y * c67.y;
    float d2 = a01.x * s0.x + a01.y * s0.y + a23.x * s0.z + a23.y * s0.w +
               a45.x * s1.x + a45.y * s1.y + a67.x * s1.z + a67.y * s1.w;
#pragma unroll
    for (int off = 32; off; off >>= 1) {
      d1 += __shfl_xor(d1, off);
      d2 += __shfl_xor(d2, off);
    }
    if (lane == 0) {
      float lse = __logf(sexp[t]);
      float cm = (float)cnt[g * NSLOT + gs];
      wsum += 0.5f * SCALE * (d2 * 10.0f / cm + d1 * 10.0f - 2.0f * lse);
    }
  }
  if (lane == 0) sh[wid] = wsum;
  __syncthreads();
  if (threadIdx.x == 0)
    atomicAdd(out, (sh[0] + sh[1] + sh[2] + sh[3]) * (1.0f / NTOKENS));
}

extern "C" void kernel_launch(void* const* d_in, const int* in_sizes, int n_in,
                              void* d_out, int out_size, void* d_ws, size_t ws_size,
                              hipStream_t stream) {
  const float* ft = (const float*)d_in[0];
  const float* fc = (const float*)d_in[1];
  const float* masks = (const float*)d_in[2];
  char* ws = (char*)d_ws;

  unsigned char* ft8 = (unsigned char*)(ws);                 // 33554432
  unsigned char* fc8 = (unsigned char*)(ws + 33554432);      // 33554432
  int* grp = (int*)(ws + 67108864);                          // 262144
  int* cnt = (int*)(ws + 67371008);                          // 2048
  float* fcsum = (float*)(ws + 67373056);                    // 1048576
  float* sexp = (float*)(ws + 68421632);                     // 262144
  float* part = (float*)(ws + 68683776);                     // 33554432
  float* out = (float*)d_out;

  static int lds_attr_set = 0;
  if (!lds_attr_set) {
    (void)hipFuncSetAttribute((const void*)k_pair,
                              hipFuncAttributeMaxDynamicSharedMemorySize, 131072);
    lds_attr_set = 1;
  }

  (void)hipMemsetAsync(cnt, 0, GN * NSLOT * sizeof(int), stream);
  (void)hipMemsetAsync(out, 0, sizeof(float), stream);
  k_norm2<<<NORMB, 256, 0, stream>>>(ft, fc, ft8, fc8);
  k_grp<<<NTOKENS / 256, 256, 0, stream>>>(masks, grp, cnt);
  k_fcsum_part<<<GN * NCH, 256, 0, stream>>>(fc8, grp, part);
  k_fcsum_red<<<GN * NSLOT * CD / 256, 256, 0, stream>>>(part, fcsum);
  k_pair<<<GN * (MT / BM), 512, 131072, stream>>>(ft8, fc8, sexp);
  k_loss<<<1024, 256, 0, stream>>>(ft8, fc8, fcsum, grp, cnt, sexp, out);
}

// Round 18
// 221.822 us; speedup vs baseline: 1.0363x; 1.0363x over previous
//
#include <hip/hip_runtime.h>

#define GN 32
#define MT 2048
#define CD 512
#define NSLOT 16
#define NTOKENS 65536
#define SCALE -1.4285714285714286f

typedef float f32x4 __attribute__((ext_vector_type(4)));
typedef float f32x2 __attribute__((ext_vector_type(2)));
typedef int i32x4 __attribute__((ext_vector_type(4)));
typedef int i32x8 __attribute__((ext_vector_type(8)));

// ---- OCP e4m3fn encode/decode: hardware cvt when available, manual fallback ----
__device__ __forceinline__ float fp82f_sw(unsigned b) {
  unsigned s = (b & 0x80u) << 24;
  unsigned em = b & 0x7fu;
  float v;
  if (em >= 8)
    v = __uint_as_float((((em >> 3) + 120u) << 23) | ((em & 7u) << 20));
  else
    v = (float)em * 0x1p-9f;
  return __uint_as_float(__float_as_uint(v) | s);
}

#if __has_builtin(__builtin_amdgcn_cvt_pk_f32_fp8)
template <bool HI>
__device__ __forceinline__ f32x2 fp8dec2(unsigned word) {
  return __builtin_amdgcn_cvt_pk_f32_fp8((int)word, HI);
}
#else
template <bool HI>
__device__ __forceinline__ f32x2 fp8dec2(unsigned word) {
  unsigned w = HI ? (word >> 16) : word;
  f32x2 r;
  r.x = fp82f_sw(w & 0xffu);
  r.y = fp82f_sw((w >> 8) & 0xffu);
  return r;
}
#endif

__device__ __forceinline__ unsigned char f2fp8_sw(float f) {
  unsigned s = (__float_as_uint(f) >> 24) & 0x80u;
  float a = fabsf(f);
  unsigned char r;
  if (a >= 0x1p-6f) {
    int e = (int)(__float_as_uint(a) >> 23) - 127;
    int qi = (int)rintf(__builtin_ldexpf(a, 3 - e));
    if (qi == 16) { qi = 8; ++e; }
    r = (unsigned char)(((e + 7) << 3) | (qi - 8));
  } else {
    r = (unsigned char)(int)rintf(a * 512.0f);
  }
  return (unsigned char)(r | s);
}

#if __has_builtin(__builtin_amdgcn_cvt_pk_fp8_f32)
__device__ __forceinline__ unsigned pk4fp8(float a, float b, float c, float d) {
  int w = __builtin_amdgcn_cvt_pk_fp8_f32(a, b, 0, false);
  w = __builtin_amdgcn_cvt_pk_fp8_f32(c, d, w, true);
  return (unsigned)w;
}
#else
__device__ __forceinline__ unsigned pk4fp8(float a, float b, float c, float d) {
  return (unsigned)f2fp8_sw(a) | ((unsigned)f2fp8_sw(b) << 8) |
         ((unsigned)f2fp8_sw(c) << 16) | ((unsigned)f2fp8_sw(d) << 24);
}
#endif

__device__ __forceinline__ void gload16(const void* g, const void* l) {
  __builtin_amdgcn_global_load_lds((const __attribute__((address_space(1))) unsigned*)g,
                                   (__attribute__((address_space(3))) unsigned*)(
                                       (unsigned long)l),
                                   16, 0, 0);
}

// K1: L2-normalize rows of [NTOKENS,512] fp32 -> fp8 e4m3 for BOTH inputs.
// R11 form — best measured end-to-end total (222.86 us). Six alternative
// structures (grid-stride, VGPR prefetch, LDS dbuf x2, 2-row, deep-ILP) all
// measured equal-or-worse; per-dispatch rocprof readings are inflated, totals
// are the reliable signal.
__global__ __launch_bounds__(256) void k_norm2(const float* __restrict__ a,
                                               const float* __restrict__ b,
                                               unsigned char* __restrict__ oa,
                                               unsigned char* __restrict__ ob) {
  int wid = threadIdx.x >> 6, lane = threadIdx.x & 63;
  long idx = (long)blockIdx.x * 4 + wid;  // 0..131071
  const float* in = (idx < NTOKENS) ? a : b;
  unsigned char* out = (idx < NTOKENS) ? oa : ob;
  long row = idx & (NTOKENS - 1);
  const float4* src = reinterpret_cast<const float4*>(in + row * CD);
  float4 v0 = src[2 * lane];
  float4 v1 = src[2 * lane + 1];
  float ss = v0.x * v0.x + v0.y * v0.y + v0.z * v0.z + v0.w * v0.w +
             v1.x * v1.x + v1.y * v1.y + v1.z * v1.z + v1.w * v1.w;
#pragma unroll
  for (int off = 32; off; off >>= 1) ss += __shfl_xor(ss, off);
  float rn = 1.0f / fmaxf(sqrtf(ss), 1e-12f);
  uint2 p;
  p.x = pk4fp8(v0.x * rn, v0.y * rn, v0.z * rn, v0.w * rn);
  p.y = pk4fp8(v1.x * rn, v1.y * rn, v1.z * rn, v1.w * rn);
  reinterpret_cast<uint2*>(out + row * CD)[lane] = p;
}

// K2: argmax over slot dim + per-(group,slot) histogram
__global__ __launch_bounds__(256) void k_grp(const float* __restrict__ masks,
                                             int* __restrict__ grp, int* __restrict__ cnt) {
  int t = blockIdx.x * 256 + threadIdx.x;
  int bt = t >> 10, n = t & 1023;
  const float* p = masks + (size_t)bt * NSLOT * 1024 + n;
  float bv = p[0];
  int bs = 0;
#pragma unroll
  for (int s = 1; s < NSLOT; ++s) {
    float v = p[(size_t)s * 1024];
    if (v > bv) { bv = v; bs = s; }
  }
  grp[t] = bs;
  atomicAdd(&cnt[(t >> 11) * NSLOT + bs], 1);
}

// K3a: partial fcsum via LDS-indexed accumulation (proven R8 version, hw decode).
#define FCH 64
#define NCH (MT / FCH)  // 32
__global__ __launch_bounds__(256, 4) void k_fcsum_part(const unsigned char* __restrict__ fc8,
                                                       const int* __restrict__ grp,
                                                       float* __restrict__ part) {
  __shared__ float accs[NSLOT * CD];
  __shared__ int gsh[FCH];
  int g = blockIdx.x >> 5;
  int ch = blockIdx.x & 31;
  int t = threadIdx.x;
  if (t < FCH) gsh[t] = grp[g * MT + ch * FCH + t];
#pragma unroll
  for (int i = 0; i < NSLOT * CD / 256; ++i) accs[i * 256 + t] = 0.f;
  __syncthreads();
  const unsigned char* base = fc8 + ((size_t)g * MT + ch * FCH) * CD + 2 * t;
#pragma unroll 4
  for (int n = 0; n < FCH; ++n) {
    unsigned u = *(const unsigned short*)(base + (size_t)n * CD);
    int gs = gsh[n];
    f32x2 v = fp8dec2<false>(u);
    float* p = &accs[gs * CD + 2 * t];
    p[0] += v.x;
    p[1] += v.y;
  }
  __syncthreads();
  float* dst = part + (size_t)(g * NCH + ch) * (NSLOT * CD);
#pragma unroll
  for (int i = 0; i < NSLOT * CD / 256; ++i) dst[i * 256 + t] = accs[i * 256 + t];
}

// K3b: reduce partials over the 32 chunks
__global__ __launch_bounds__(256) void k_fcsum_red(const float* __restrict__ part,
                                                   float* __restrict__ fcsum) {
  int idx = blockIdx.x * 256 + threadIdx.x;  // < GN*NSLOT*CD = 262144
  int g = idx >> 13;
  int sc = idx & 8191;
  float s = 0.f;
#pragma unroll
  for (int ch = 0; ch < NCH; ++ch)
    s += part[(size_t)(g * NCH + ch) * (NSLOT * CD) + sc];
  fcsum[idx] = s;
}

// K4: MX-fp8 256x256-tile pair kernel — exact R9 structure (99 us proven).
// Depth-2 schedules twice-failed on register budget (R6 hoist-spill, R15
// barrier-in-unroll spill) — schedule frozen at depth-1.
#define BM 256
#define BN 256
#define BKB 128
#define NTILE 32  // 8 col-tiles x 4 k-tiles

__global__ __launch_bounds__(512, 2) void k_pair(const unsigned char* __restrict__ ft8,
                                                 const unsigned char* __restrict__ fc8,
                                                 float* __restrict__ sexp_out) {
  extern __shared__ char smem[];  // A0[32K] A1[32K] B0[32K] B1[32K]

  const int b = blockIdx.x;
  const int xcd = b & 7;
  const int slot = b >> 3;
  const int g = (slot >> 3) * 8 + xcd;
  const int rt = slot & 7;
  const int r0 = rt * BM;

  const int tid = threadIdx.x;
  const int lane = tid & 63;
  const int wid = tid >> 6;
  const int wr = wid >> 2;   // 0..1
  const int wc = wid & 3;    // 0..3
  const int frow = lane & 15;
  const int l4 = lane >> 4;  // 0..3 -> k-block l4*32 bytes
  const int f7 = frow & 7;

  const unsigned char* Abase = ft8 + (size_t)g * MT * CD;
  const unsigned char* Bbase = fc8 + (size_t)g * MT * CD;

  const int lrow = lane >> 3;                  // 0..7
  const int koff = ((lane & 7) ^ lrow) << 4;   // pre-swizzled source chunk (bytes)

  const int c0off = ((2 * l4) ^ f7) << 4;
  const int c1off = ((2 * l4 + 1) ^ f7) << 4;
  const int baseA = (wr * 128 + frow) * 128;
  const int baseB = (wc * 64 + frow) * 128;

  f32x4 acc[8][4];
#pragma unroll
  for (int m = 0; m < 8; ++m)
#pragma unroll
    for (int n = 0; n < 4; ++n) acc[m][n] = (f32x4){0.f, 0.f, 0.f, 0.f};
  float sexp_loc[8][4];
#pragma unroll
  for (int m = 0; m < 8; ++m)
#pragma unroll
    for (int r = 0; r < 4; ++r) sexp_loc[m][r] = 0.f;

#define STAGE(TT, PB)                                                         \
  {                                                                           \
    const int kk_ = ((TT) & 3) * BKB;                                         \
    const int n0_ = ((TT) >> 2) * BN;                                         \
    char* dA_ = smem + (size_t)(PB)*32768;                                    \
    char* dB_ = smem + 65536 + (size_t)(PB)*32768;                            \
    _Pragma("unroll") for (int j_ = 0; j_ < 4; ++j_) {                        \
      const int rb_ = wid * 32 + j_ * 8;                                      \
      gload16(Abase + (size_t)(r0 + rb_ + lrow) * CD + kk_ + koff,            \
              dA_ + (size_t)rb_ * BKB);                                       \
      gload16(Bbase + (size_t)(n0_ + rb_ + lrow) * CD + kk_ + koff,           \
              dB_ + (size_t)rb_ * BKB);                                       \
    }                                                                         \
  }

  STAGE(0, 0)
  __syncthreads();

  int pb = 0;
  for (int t = 0; t < NTILE; ++t) {
    if (t + 1 < NTILE) STAGE(t + 1, pb ^ 1)

    const char* cA = smem + (size_t)pb * 32768;
    const char* cB = smem + 65536 + (size_t)pb * 32768;
    __builtin_amdgcn_s_setprio(1);
    i32x8 bfv[4];
#pragma unroll
    for (int n = 0; n < 4; ++n) {
      i32x4 lo = *(const i32x4*)(cB + baseB + n * 2048 + c0off);
      i32x4 hi = *(const i32x4*)(cB + baseB + n * 2048 + c1off);
      bfv[n] = __builtin_shufflevector(lo, hi, 0, 1, 2, 3, 4, 5, 6, 7);
    }
#pragma unroll
    for (int m = 0; m < 8; ++m) {
      i32x4 lo = *(const i32x4*)(cA + baseA + m * 2048 + c0off);
      i32x4 hi = *(const i32x4*)(cA + baseA + m * 2048 + c1off);
      i32x8 af = __builtin_shufflevector(lo, hi, 0, 1, 2, 3, 4, 5, 6, 7);
#pragma unroll
      for (int n = 0; n < 4; ++n)
        acc[m][n] = __builtin_amdgcn_mfma_scale_f32_16x16x128_f8f6f4(
            af, bfv[n], acc[m][n], 0, 0, 0, 0x7f7f7f7f, 0, 0x7f7f7f7f);
    }
    __builtin_amdgcn_s_setprio(0);

    if ((t & 3) == 3) {
#pragma unroll
      for (int m = 0; m < 8; ++m)
#pragma unroll
        for (int r = 0; r < 4; ++r) {
          float e = 0.f;
#pragma unroll
          for (int n = 0; n < 4; ++n) e += exp2f(acc[m][n][r] * 14.4269504089f);
          sexp_loc[m][r] += e;
        }
#pragma unroll
      for (int m = 0; m < 8; ++m)
#pragma unroll
        for (int n = 0; n < 4; ++n) acc[m][n] = (f32x4){0.f, 0.f, 0.f, 0.f};
    }

    __syncthreads();
    pb ^= 1;
  }
#undef STAGE

#pragma unroll
  for (int m = 0; m < 8; ++m)
#pragma unroll
    for (int r = 0; r < 4; ++r) {
      float v = sexp_loc[m][r];
      v += __shfl_xor(v, 1);
      v += __shfl_xor(v, 2);
      v += __shfl_xor(v, 4);
      v += __shfl_xor(v, 8);
      sexp_loc[m][r] = v;
    }
  __syncthreads();
  float* scr = (float*)smem;  // [8 waves][128 rows]
  if (frow == 0) {
#pragma unroll
    for (int m = 0; m < 8; ++m)
#pragma unroll
      for (int r = 0; r < 4; ++r) scr[wid * 128 + m * 16 + l4 * 4 + r] = sexp_loc[m][r];
  }
  __syncthreads();
  if (tid < 256) {
    int wrr = tid >> 7, rl = tid & 127;
    float s = scr[(wrr * 4 + 0) * 128 + rl] + scr[(wrr * 4 + 1) * 128 + rl] +
              scr[(wrr * 4 + 2) * 128 + rl] + scr[(wrr * 4 + 3) * 128 + rl];
    sexp_out[(size_t)g * MT + r0 + tid] = s;
  }
}

// K5: per-token loss fused with final mean (fp8 inputs, hw decode)
__global__ __launch_bounds__(256) void k_loss(const unsigned char* __restrict__ ft8,
                                              const unsigned char* __restrict__ fc8,
                                              const float* __restrict__ fcsum,
                                              const int* __restrict__ grp,
                                              const int* __restrict__ cnt,
                                              const float* __restrict__ sexp,
                                              float* __restrict__ out) {
  __shared__ float sh[4];
  int wid = threadIdx.x >> 6, lane = threadIdx.x & 63;
  float wsum = 0.f;
  for (int t = blockIdx.x * 4 + wid; t < NTOKENS; t += 4096) {
    int g = t >> 11;
    uint2 u1 = reinterpret_cast<const uint2*>(ft8 + (size_t)t * CD)[lane];
    uint2 u2 = reinterpret_cast<const uint2*>(fc8 + (size_t)t * CD)[lane];
    int gs = grp[t];
    const float4* srv = (const float4*)(fcsum + ((size_t)g * NSLOT + gs) * CD);
    float4 s0 = srv[2 * lane];
    float4 s1 = srv[2 * lane + 1];
    f32x2 a01 = fp8dec2<false>(u1.x), a23 = fp8dec2<true>(u1.x);
    f32x2 a45 = fp8dec2<false>(u1.y), a67 = fp8dec2<true>(u1.y);
    f32x2 c01 = fp8dec2<false>(u2.x), c23 = fp8dec2<true>(u2.x);
    f32x2 c45 = fp8dec2<false>(u2.y), c67 = fp8dec2<true>(u2.y);
    float d1 = a01.x * c01.x + a01.y * c01.y + a23.x * c23.x + a23.y * c23.y +
               a45.x * c45.x + a45.y * c45.y + a67.x * c67.x + a67.y * c67.y;
    float d2 = a01.x * s0.x + a01.y * s0.y + a23.x * s0.z + a23.y * s0.w +
               a45.x * s1.x + a45.y * s1.y + a67.x * s1.z + a67.y * s1.w;
#pragma unroll
    for (int off = 32; off; off >>= 1) {
      d1 += __shfl_xor(d1, off);
      d2 += __shfl_xor(d2, off);
    }
    if (lane == 0) {
      float lse = __logf(sexp[t]);
      float cm = (float)cnt[g * NSLOT + gs];
      wsum += 0.5f * SCALE * (d2 * 10.0f / cm + d1 * 10.0f - 2.0f * lse);
    }
  }
  if (lane == 0) sh[wid] = wsum;
  __syncthreads();
  if (threadIdx.x == 0)
    atomicAdd(out, (sh[0] + sh[1] + sh[2] + sh[3]) * (1.0f / NTOKENS));
}

extern "C" void kernel_launch(void* const* d_in, const int* in_sizes, int n_in,
                              void* d_out, int out_size, void* d_ws, size_t ws_size,
                              hipStream_t stream) {
  const float* ft = (const float*)d_in[0];
  const float* fc = (const float*)d_in[1];
  const float* masks = (const float*)d_in[2];
  char* ws = (char*)d_ws;

  unsigned char* ft8 = (unsigned char*)(ws);                 // 33554432
  unsigned char* fc8 = (unsigned char*)(ws + 33554432);      // 33554432
  int* grp = (int*)(ws + 67108864);                          // 262144
  int* cnt = (int*)(ws + 67371008);                          // 2048
  float* fcsum = (float*)(ws + 67373056);                    // 1048576
  float* sexp = (float*)(ws + 68421632);                     // 262144
  float* part = (float*)(ws + 68683776);                     // 33554432
  float* out = (float*)d_out;

  static int lds_attr_set = 0;
  if (!lds_attr_set) {
    (void)hipFuncSetAttribute((const void*)k_pair,
                              hipFuncAttributeMaxDynamicSharedMemorySize, 131072);
    lds_attr_set = 1;
  }

  (void)hipMemsetAsync(cnt, 0, GN * NSLOT * sizeof(int), stream);
  (void)hipMemsetAsync(out, 0, sizeof(float), stream);
  k_norm2<<<NTOKENS / 2, 256, 0, stream>>>(ft, fc, ft8, fc8);
  k_grp<<<NTOKENS / 256, 256, 0, stream>>>(masks, grp, cnt);
  k_fcsum_part<<<GN * NCH, 256, 0, stream>>>(fc8, grp, part);
  k_fcsum_red<<<GN * NSLOT * CD / 256, 256, 0, stream>>>(part, fcsum);
  k_pair<<<GN * (MT / BM), 512, 131072, stream>>>(ft8, fc8, sexp);
  k_loss<<<1024, 256, 0, stream>>>(ft8, fc8, fcsum, grp, cnt, sexp, out);
}